// Round 4
// baseline (106.004 us; speedup 1.0000x reference)
//
#include <hip/hip_runtime.h>

// Problem constants (match reference.py)
#define NB   65536   // trajectories
#define HALF 32768   // trajectories per half (2 trajectories per thread)
#define NT   512     // time points (NT-1 steps)

typedef float f32x2 __attribute__((ext_vector_type(2)));

// 2 trajectories per thread, packed as f32x2 lanes: bb=(b0,b1), ss=(s0,s1).
// 32768 threads = 256 blocks x 128 = 1 block/CU, 2 waves/CU. Latency-bound
// regime: the two independent chains per thread fill each other's stall gaps.
__global__ __launch_bounds__(128) void rk4_biosystem_kernel(
    const float* __restrict__ y0,
    const float* __restrict__ t_eval,
    const float* __restrict__ D_seq,
    const float* __restrict__ K_m_p,
    const float* __restrict__ s_e_p,
    const float* __restrict__ mu_max_p,
    float* __restrict__ out)
{
    __shared__ float s_dt[NT - 1];
    __shared__ float s_D[NT - 1];

    const int tid = threadIdx.x;
    // Stage per-step uniforms into LDS (dt exactly as reference: t[i+1]-t[i])
    for (int i = tid; i < NT - 1; i += 128) {
        s_dt[i] = t_eval[i + 1] - t_eval[i];
        s_D[i]  = D_seq[i];
    }
    __syncthreads();

    const float K_m    = K_m_p[0];
    const float s_e    = s_e_p[0];
    const float mu_max = mu_max_p[0];

    const int gid = blockIdx.x * 128 + tid;   // 0..32767

    // Load both trajectories' initial states
    const f32x2* __restrict__ y0v = (const f32x2*)y0;
    f32x2 ya = y0v[gid];          // (b0, s0)
    f32x2 yb = y0v[gid + HALF];   // (b1, s1)
    f32x2 bb; bb.x = ya.x; bb.y = yb.x;   // (b0, b1)
    f32x2 ss; ss.x = ya.y; ss.y = yb.y;   // (s0, s1)

    f32x2* __restrict__ out2 = (f32x2*)out;  // out[t][traj][2] as vec2

    // out[0] = y0
    __builtin_nontemporal_store(ya, &out2[gid]);
    __builtin_nontemporal_store(yb, &out2[gid + HALF]);

    // Software-pipelined LDS reads (1-ahead prefetch)
    float dt_c = s_dt[0];
    float D_c  = s_D[0];

    // rhs packed over 2 trajectories:
    //   rho = mu_max*s/(K_m+s); kb = rho*b - D*b; ks = D*(s_e-s) - rho*b
    #define RHS(BB, SS, KB, KS)                                   \
        {                                                         \
            f32x2 den = K_m + (SS);                               \
            f32x2 inv;                                            \
            inv.x = __builtin_amdgcn_rcpf(den.x);                 \
            inv.y = __builtin_amdgcn_rcpf(den.y);                 \
            f32x2 rb = (mu_max * (SS)) * (inv * (BB));            \
            KB = rb - D * (BB);                                   \
            KS = D * (s_e - (SS)) - rb;                           \
        }

    #pragma unroll 2
    for (int t = 0; t < NT - 1; ++t) {
        const float dt = dt_c;
        const float D  = D_c;
        // prefetch next step's uniforms (clamped index on last iteration)
        const int tn = (t < NT - 2) ? (t + 1) : t;
        dt_c = s_dt[tn];
        D_c  = s_D[tn];

        f32x2 k1b, k1s, k2b, k2s, k3b, k3s, k4b, k4s;
        RHS(bb, ss, k1b, k1s);
        const float h2 = dt * 0.5f;
        RHS(bb + h2 * k1b, ss + h2 * k1s, k2b, k2s);
        RHS(bb + h2 * k2b, ss + h2 * k2s, k3b, k3s);
        RHS(bb + dt * k3b, ss + dt * k3s, k4b, k4s);

        const float h6 = dt * (1.0f / 6.0f);
        bb = bb + h6 * (k1b + 2.0f * k2b + 2.0f * k3b + k4b);
        ss = ss + h6 * (k1s + 2.0f * k2s + 2.0f * k3s + k4s);

        f32x2 v0; v0.x = bb.x; v0.y = ss.x;
        f32x2 v1; v1.x = bb.y; v1.y = ss.y;
        const int base = (t + 1) * NB + gid;
        __builtin_nontemporal_store(v0, &out2[base]);
        __builtin_nontemporal_store(v1, &out2[base + HALF]);
    }
    #undef RHS
}

extern "C" void kernel_launch(void* const* d_in, const int* in_sizes, int n_in,
                              void* d_out, int out_size, void* d_ws, size_t ws_size,
                              hipStream_t stream) {
    const float* y0     = (const float*)d_in[0];
    const float* t_eval = (const float*)d_in[1];
    const float* D_seq  = (const float*)d_in[2];
    const float* K_m    = (const float*)d_in[3];
    const float* s_e    = (const float*)d_in[4];
    const float* mu_max = (const float*)d_in[5];
    float* out = (float*)d_out;

    dim3 grid(HALF / 128);   // 256 blocks -> 1 per CU
    dim3 block(128);
    rk4_biosystem_kernel<<<grid, block, 0, stream>>>(y0, t_eval, D_seq, K_m, s_e, mu_max, out);
}

// Round 5
// 69.078 us; speedup vs baseline: 1.5346x; 1.5346x over previous
//
#include <hip/hip_runtime.h>

// Problem constants (match reference.py)
#define NB 65536   // trajectories
#define NT 512     // time points (NT-1 steps)

typedef float f32x2 __attribute__((ext_vector_type(2)));

// 1 trajectory per thread: 65536 threads = 1024 waves = 1 wave/SIMD (max TLP
// for this problem size). Latency-bound -> pipeline everything explicitly:
//  - distance-2 LDS prefetch of per-step uniforms (dt, D)
//  - unroll 4 so store-data registers rotate (no distance-1 vmcnt waits)
//  - rcp off the critical path: rb = (mu_max*s*b) * rcp(K_m+s)
__global__ __launch_bounds__(256) void rk4_biosystem_kernel(
    const float* __restrict__ y0,
    const float* __restrict__ t_eval,
    const float* __restrict__ D_seq,
    const float* __restrict__ K_m_p,
    const float* __restrict__ s_e_p,
    const float* __restrict__ mu_max_p,
    float* __restrict__ out)
{
    __shared__ float s_dt[NT - 1];
    __shared__ float s_D[NT - 1];

    const int tid = threadIdx.x;
    // Stage per-step uniforms into LDS (dt exactly as reference: t[i+1]-t[i])
    for (int i = tid; i < NT - 1; i += 256) {
        s_dt[i] = t_eval[i + 1] - t_eval[i];
        s_D[i]  = D_seq[i];
    }
    __syncthreads();

    const float K_m    = K_m_p[0];
    const float s_e    = s_e_p[0];
    const float mu_max = mu_max_p[0];

    const int traj = blockIdx.x * 256 + tid;

    float b = y0[traj * 2 + 0];
    float s = y0[traj * 2 + 1];

    f32x2* __restrict__ out2 = (f32x2*)out;  // out[t][traj][2] as vec2

    // out[0] = y0
    {
        f32x2 v; v.x = b; v.y = s;
        __builtin_nontemporal_store(v, &out2[traj]);
    }

    // Distance-2 software pipeline for the per-step uniforms.
    float dt0 = s_dt[0], D0 = s_D[0];
    float dt1 = s_dt[1], D1 = s_D[1];

    // rhs: rho*b = mu_max*s*b / (K_m+s); db = rho*b - D*b; ds = D*(s_e-s) - rho*b
    // num = mu_max*s*b computed in parallel with the rcp -> shorter chain.
    #define RHS(bb, ss, db, ds)                                  \
        {                                                        \
            float inv = __builtin_amdgcn_rcpf(K_m + (ss));       \
            float num = (mu_max * (ss)) * (bb);                  \
            float rb  = num * inv;                               \
            db = __builtin_fmaf(-D, (bb), rb);                   \
            ds = __builtin_fmaf(D, s_e - (ss), -rb);             \
        }

    #pragma unroll 4
    for (int t = 0; t < NT - 1; ++t) {
        const float dt = dt0;
        const float D  = D0;
        // rotate the pipeline; fetch step t+2 (clamped)
        dt0 = dt1; D0 = D1;
        const int tn = (t < NT - 3) ? (t + 2) : (NT - 2);
        dt1 = s_dt[tn];
        D1  = s_D[tn];

        float k1b, k1s, k2b, k2s, k3b, k3s, k4b, k4s;
        RHS(b, s, k1b, k1s);
        const float h2 = dt * 0.5f;
        RHS(__builtin_fmaf(h2, k1b, b), __builtin_fmaf(h2, k1s, s), k2b, k2s);
        RHS(__builtin_fmaf(h2, k2b, b), __builtin_fmaf(h2, k2s, s), k3b, k3s);
        RHS(__builtin_fmaf(dt, k3b, b), __builtin_fmaf(dt, k3s, s), k4b, k4s);

        // incremental k-sums (parallel trees)
        const float sb  = (k1b + k4b) + 2.0f * (k2b + k3b);
        const float ss_ = (k1s + k4s) + 2.0f * (k2s + k3s);
        const float h6 = dt * (1.0f / 6.0f);
        b = __builtin_fmaf(h6, sb, b);
        s = __builtin_fmaf(h6, ss_, s);

        f32x2 v; v.x = b; v.y = s;
        __builtin_nontemporal_store(v, &out2[(t + 1) * NB + traj]);
    }
    #undef RHS
}

extern "C" void kernel_launch(void* const* d_in, const int* in_sizes, int n_in,
                              void* d_out, int out_size, void* d_ws, size_t ws_size,
                              hipStream_t stream) {
    const float* y0     = (const float*)d_in[0];
    const float* t_eval = (const float*)d_in[1];
    const float* D_seq  = (const float*)d_in[2];
    const float* K_m    = (const float*)d_in[3];
    const float* s_e    = (const float*)d_in[4];
    const float* mu_max = (const float*)d_in[5];
    float* out = (float*)d_out;

    dim3 grid(NB / 256);
    dim3 block(256);
    rk4_biosystem_kernel<<<grid, block, 0, stream>>>(y0, t_eval, D_seq, K_m, s_e, mu_max, out);
}

// Round 6
// 63.308 us; speedup vs baseline: 1.6744x; 1.0911x over previous
//
#include <hip/hip_runtime.h>

// Problem constants (match reference.py)
#define NB 65536   // trajectories
#define NT 512     // time points (NT-1 steps)

typedef float f32x2 __attribute__((ext_vector_type(2)));

// 1 trajectory per thread: 65536 threads = 1024 waves = 1 wave/SIMD (max TLP).
// Store path: plain (cached) stores so L2 absorbs completion latency
// (nontemporal bypassed L2 and exposed ~900cy HBM latency to vmcnt);
// unroll 8 so store-data registers rotate with reuse distance 8.
__global__ __launch_bounds__(256) void rk4_biosystem_kernel(
    const float* __restrict__ y0,
    const float* __restrict__ t_eval,
    const float* __restrict__ D_seq,
    const float* __restrict__ K_m_p,
    const float* __restrict__ s_e_p,
    const float* __restrict__ mu_max_p,
    float* __restrict__ out)
{
    __shared__ float s_dt[NT - 1];
    __shared__ float s_D[NT - 1];

    const int tid = threadIdx.x;
    // Stage per-step uniforms into LDS (dt exactly as reference: t[i+1]-t[i])
    for (int i = tid; i < NT - 1; i += 256) {
        s_dt[i] = t_eval[i + 1] - t_eval[i];
        s_D[i]  = D_seq[i];
    }
    __syncthreads();

    const float K_m    = K_m_p[0];
    const float s_e    = s_e_p[0];
    const float mu_max = mu_max_p[0];

    const int traj = blockIdx.x * 256 + tid;

    float b = y0[traj * 2 + 0];
    float s = y0[traj * 2 + 1];

    f32x2* __restrict__ out2 = (f32x2*)out;  // out[t][traj][2] as vec2

    // out[0] = y0
    {
        f32x2 v; v.x = b; v.y = s;
        out2[traj] = v;
    }

    // Distance-2 software pipeline for the per-step uniforms.
    float dt0 = s_dt[0], D0 = s_D[0];
    float dt1 = s_dt[1], D1 = s_D[1];

    // rhs: rho*b = mu_max*s*b / (K_m+s); db = rho*b - D*b; ds = D*(s_e-s) - rho*b
    // num = mu_max*s*b computed in parallel with the rcp -> shorter chain.
    #define RHS(bb, ss, db, ds)                                  \
        {                                                        \
            float inv = __builtin_amdgcn_rcpf(K_m + (ss));       \
            float num = (mu_max * (ss)) * (bb);                  \
            float rb  = num * inv;                               \
            db = __builtin_fmaf(-D, (bb), rb);                   \
            ds = __builtin_fmaf(D, s_e - (ss), -rb);             \
        }

    #pragma unroll 8
    for (int t = 0; t < NT - 1; ++t) {
        const float dt = dt0;
        const float D  = D0;
        // rotate the pipeline; fetch step t+2 (clamped)
        dt0 = dt1; D0 = D1;
        const int tn = (t < NT - 3) ? (t + 2) : (NT - 2);
        dt1 = s_dt[tn];
        D1  = s_D[tn];

        float k1b, k1s, k2b, k2s, k3b, k3s, k4b, k4s;
        RHS(b, s, k1b, k1s);
        const float h2 = dt * 0.5f;
        RHS(__builtin_fmaf(h2, k1b, b), __builtin_fmaf(h2, k1s, s), k2b, k2s);
        RHS(__builtin_fmaf(h2, k2b, b), __builtin_fmaf(h2, k2s, s), k3b, k3s);
        RHS(__builtin_fmaf(dt, k3b, b), __builtin_fmaf(dt, k3s, s), k4b, k4s);

        // parallel reduction trees for the k-sums
        const float sb  = (k1b + k4b) + 2.0f * (k2b + k3b);
        const float ss_ = (k1s + k4s) + 2.0f * (k2s + k3s);
        const float h6 = dt * (1.0f / 6.0f);
        b = __builtin_fmaf(h6, sb, b);
        s = __builtin_fmaf(h6, ss_, s);

        f32x2 v; v.x = b; v.y = s;
        out2[(t + 1) * NB + traj] = v;
    }
    #undef RHS
}

extern "C" void kernel_launch(void* const* d_in, const int* in_sizes, int n_in,
                              void* d_out, int out_size, void* d_ws, size_t ws_size,
                              hipStream_t stream) {
    const float* y0     = (const float*)d_in[0];
    const float* t_eval = (const float*)d_in[1];
    const float* D_seq  = (const float*)d_in[2];
    const float* K_m    = (const float*)d_in[3];
    const float* s_e    = (const float*)d_in[4];
    const float* mu_max = (const float*)d_in[5];
    float* out = (float*)d_out;

    dim3 grid(NB / 256);
    dim3 block(256);
    rk4_biosystem_kernel<<<grid, block, 0, stream>>>(y0, t_eval, D_seq, K_m, s_e, mu_max, out);
}